// Round 10
// baseline (178.468 us; speedup 1.0000x reference)
//
#include <hip/hip_runtime.h>
#include <hip/hip_bf16.h>
#include <stdint.h>

#define B_ 8
#define N_ 1024
#define E_ 768
#define H_ 12
#define HD_ 64
#define M_ (B_ * N_)   // 8192 rows

typedef __attribute__((ext_vector_type(8))) short bf8_t;   // 8 x bf16 (4 VGPR)
typedef __attribute__((ext_vector_type(4))) float f4_t;    // 4 x f32

__device__ __forceinline__ unsigned short f2bf(float f) {
  unsigned u = __builtin_bit_cast(unsigned, f);
  unsigned r = (u + 0x7fffu + ((u >> 16) & 1u)) >> 16;  // RNE
  return (unsigned short)r;
}

__device__ __forceinline__ unsigned cvt_pk_bf16(float lo, float hi) {
  unsigned r;
  asm("v_cvt_pk_bf16_f32 %0, %1, %2" : "=v"(r) : "v"(lo), "v"(hi));
  return r;
}

// single-instruction exp2 (libm exp2f lowers to an __ocml call without
// fast-math; v_exp_f32 is the hardware op, denorm-flush is fine here)
__device__ __forceinline__ float exp2_hw(float x) {
  float r;
  asm("v_exp_f32 %0, %1" : "=v"(r) : "v"(x));
  return r;
}

__device__ __forceinline__ void load_lds16(const void* g, void* l) {
  __builtin_amdgcn_global_load_lds(
      (__attribute__((address_space(1))) void*)(g),
      (__attribute__((address_space(3))) void*)(l), 16, 0, 0);
}

// counted wait: prefetch loads stay in flight across the barrier (T4)
#define WAITV(N)                                        \
  asm volatile("s_waitcnt vmcnt(" #N ")" ::: "memory"); \
  __builtin_amdgcn_sched_barrier(0);                    \
  __builtin_amdgcn_s_barrier();                         \
  __builtin_amdgcn_sched_barrier(0);

#define BAR2()                          \
  __builtin_amdgcn_sched_barrier(0);    \
  __builtin_amdgcn_s_barrier();         \
  __builtin_amdgcn_sched_barrier(0);

// XOR swizzle on the 8-element (16B) chunk index within a 64-elem (128B) row.
__device__ __forceinline__ int swz(int row) {
  return ((row ^ (row >> 3)) & 7) << 3;
}

#define F3(a, b, c) fmaxf(fmaxf((a), (b)), (c))   // fuses to v_max3_f32

// ---------------- weight fp32 -> bf16 cast (vectorized) ----------------
__global__ void k_cast_bf16(const float* __restrict__ in,
                            unsigned short* __restrict__ out, int n4) {
  int i = blockIdx.x * blockDim.x + threadIdx.x;
  if (i < n4) {
    float4 v = ((const float4*)in)[i];
    ushort4 o;
    o.x = f2bf(v.x); o.y = f2bf(v.y); o.z = f2bf(v.z); o.w = f2bf(v.w);
    ((ushort4*)out)[i] = o;
  }
}

// ---------------- LayerNorm -> bf16 (float4 loads, ushort4 stores) ----------
__global__ __launch_bounds__(192) void k_ln(const float* __restrict__ x,
                                            const float* __restrict__ g,
                                            const float* __restrict__ bta,
                                            unsigned short* __restrict__ xn) {
  int row = blockIdx.x;  // 8192
  int t = threadIdx.x;   // 0..191, 192*4 = 768
  float4 v = ((const float4*)(x + (size_t)row * E_))[t];
  float s = v.x + v.y + v.z + v.w;
  float s2 = v.x * v.x + v.y * v.y + v.z * v.z + v.w * v.w;
  for (int off = 32; off; off >>= 1) {
    s += __shfl_xor(s, off, 64);
    s2 += __shfl_xor(s2, off, 64);
  }
  __shared__ float red[6];
  int lane = t & 63, wv = t >> 6;
  if (lane == 0) { red[wv] = s; red[3 + wv] = s2; }
  __syncthreads();
  s = red[0] + red[1] + red[2];
  s2 = red[3] + red[4] + red[5];
  float mu = s * (1.0f / E_);
  float var = s2 * (1.0f / E_) - mu * mu;
  float rstd = rsqrtf(var + 1e-5f);
  float4 gg = ((const float4*)g)[t];
  float4 bb = ((const float4*)bta)[t];
  ushort4 o;
  o.x = f2bf((v.x - mu) * rstd * gg.x + bb.x);
  o.y = f2bf((v.y - mu) * rstd * gg.y + bb.y);
  o.z = f2bf((v.z - mu) * rstd * gg.z + bb.z);
  o.w = f2bf((v.w - mu) * rstd * gg.w + bb.w);
  ((ushort4*)(xn + (size_t)row * E_))[t] = o;
}

// ---------------- QKV GEMM: 256x256 tile, 8 waves, per-wave 128x64 ------------
// FLOP/LDS-byte ratio 42.7 (vs 32 at 64x64/wave) — lifts the LDS-pipe ceiling.
// T1 XCD swizzle (nwg=288, %8==0) + T2 LDS XOR-swizzle + counted vmcnt.
__global__ __launch_bounds__(512, 2) void k_gemm_qkv(
    const unsigned short* __restrict__ A,   // [M][768] bf16 (xn)
    const unsigned short* __restrict__ W,   // [2304][768] bf16
    const float* __restrict__ bias,         // [2304]
    unsigned short* __restrict__ oQ, unsigned short* __restrict__ oK,
    unsigned short* __restrict__ oVt) {
  __shared__ unsigned short Al[2][256 * 64];  // 32 KB each
  __shared__ unsigned short Bl[2][256 * 64];  // total 128 KB
  const int K = 768, nbx = 9, nwg = 288;      // 32 x 9 blocks
  const int orig = blockIdx.y * nbx + blockIdx.x;
  const int id = (orig & 7) * (nwg >> 3) + (orig >> 3);
  const int n0 = (id % nbx) * 256, m0 = (id / nbx) * 256;
  const int tid = threadIdx.x;
  const int lane = tid & 63, wv = tid >> 6;
  const int wr = wv >> 2, wc = wv & 3;        // 2M x 4N waves of 128x64
  const int g = lane >> 4, l15 = lane & 15;
  f4_t acc[8][4] = {};

  auto stage = [&](int k0, int buf) {         // 8 loads / thread
#pragma unroll
    for (int i = 0; i < 4; ++i) {
      int e = (i * 512 + tid) * 8;            // element idx in 256x64 tile
      int r = e >> 6;
      int c = (e & 63) ^ swz(r);              // inverse-swizzled source column
      load_lds16(A + (size_t)(m0 + r) * K + (k0 + c), &Al[buf][e]);
      load_lds16(W + (size_t)(n0 + r) * K + (k0 + c), &Bl[buf][e]);
    }
  };

  const int NT = 12;                          // 768 / 64
  stage(0, 0);
  stage(64, 1);

  for (int t = 0; t < NT; ++t) {
    const int cur = t & 1;
    if (t + 1 < NT) { WAITV(8); } else { WAITV(0); }
    const unsigned short* Ac = Al[cur];
    const unsigned short* Bc = Bl[cur];
#pragma unroll
    for (int kk = 0; kk < 2; ++kk) {
      bf8_t af[8], bfr[4];
#pragma unroll
      for (int mi = 0; mi < 8; ++mi) {
        int ar = wr * 128 + mi * 16 + l15;
        af[mi] = *(const bf8_t*)&Ac[(ar * 64 + kk * 32 + g * 8) ^ swz(ar)];
      }
#pragma unroll
      for (int ni = 0; ni < 4; ++ni) {
        int br = wc * 64 + ni * 16 + l15;
        bfr[ni] = *(const bf8_t*)&Bc[(br * 64 + kk * 32 + g * 8) ^ swz(br)];
      }
      __builtin_amdgcn_s_setprio(1);
#pragma unroll
      for (int mi = 0; mi < 8; ++mi)
#pragma unroll
        for (int ni = 0; ni < 4; ++ni)
          acc[mi][ni] = __builtin_amdgcn_mfma_f32_16x16x32_bf16(
              af[mi], bfr[ni], acc[mi][ni], 0, 0, 0);
      __builtin_amdgcn_s_setprio(0);
    }
    BAR2();                                   // all waves done reading buf[cur]
    if (t + 2 < NT) stage((t + 2) << 6, cur); // refill freed buffer
  }

  // scatter epilogue: Q (*0.125*log2e) [bh][n][d], K [bh][n][d], V^T [bh][d][n]
#pragma unroll
  for (int ni = 0; ni < 4; ++ni) {
    int f = n0 + wc * 64 + ni * 16 + l15;
    float bs = bias[f];
    int which = f / E_;
    int e2 = f - which * E_;
    int h = e2 >> 6, d = e2 & 63;
#pragma unroll
    for (int mi = 0; mi < 8; ++mi) {
#pragma unroll
      for (int i = 0; i < 4; ++i) {
        int m = m0 + wr * 128 + mi * 16 + g * 4 + i;
        float val = acc[mi][ni][i] + bs;
        int bb = m >> 10, n = m & 1023;
        size_t qk = (((size_t)bb * H_ + h) * N_ + n) * HD_ + d;
        if (which == 0) oQ[qk] = f2bf(val * 0.1803368801f);  // 0.125*log2(e)
        else if (which == 1) oK[qk] = f2bf(val);
        else oVt[(((size_t)bb * H_ + h) * HD_ + d) * N_ + n] = f2bf(val);
      }
    }
  }
}

// ---------------- out-proj GEMM (128x128, 4 waves, fp32 out) ------------------
__global__ __launch_bounds__(256) void k_gemm_out(
    const unsigned short* __restrict__ A,   // [M][768] bf16 (ctx)
    const unsigned short* __restrict__ W,   // [768][768] bf16
    const float* __restrict__ bias,         // [768]
    float* __restrict__ oF) {
  __shared__ unsigned short Al[2][128 * 64];
  __shared__ unsigned short Bl[2][128 * 64];
  const int K = 768, nbx = 6, nwg = 384;
  const int orig = blockIdx.y * nbx + blockIdx.x;
  const int id = (orig & 7) * (nwg >> 3) + (orig >> 3);
  const int n0 = (id % nbx) * 128, m0 = (id / nbx) * 128;
  const int tid = threadIdx.x;
  const int lane = tid & 63, wv = tid >> 6;
  const int wr = wv >> 1, wc = wv & 1;
  const int g = lane >> 4, l15 = lane & 15;
  f4_t acc[4][4] = {};

  auto stage = [&](int k0, int buf) {       // 8 loads / thread
#pragma unroll
    for (int i = 0; i < 4; ++i) {
      int e = (i * 256 + tid) * 8;
      int r = e >> 6;
      int c = (e & 63) ^ swz(r);
      load_lds16(A + (size_t)(m0 + r) * K + (k0 + c), &Al[buf][e]);
      load_lds16(W + (size_t)(n0 + r) * K + (k0 + c), &Bl[buf][e]);
    }
  };

  const int NT = 12;
  stage(0, 0);
  stage(64, 1);

  for (int t = 0; t < NT; ++t) {
    const int cur = t & 1;
    if (t + 1 < NT) { WAITV(8); } else { WAITV(0); }
    const unsigned short* Ac = Al[cur];
    const unsigned short* Bc = Bl[cur];
#pragma unroll
    for (int kk = 0; kk < 2; ++kk) {
      bf8_t af[4], bfr[4];
#pragma unroll
      for (int mi = 0; mi < 4; ++mi) {
        int ar = wr * 64 + mi * 16 + l15;
        af[mi] = *(const bf8_t*)&Ac[(ar * 64 + kk * 32 + g * 8) ^ swz(ar)];
      }
#pragma unroll
      for (int ni = 0; ni < 4; ++ni) {
        int br = wc * 64 + ni * 16 + l15;
        bfr[ni] = *(const bf8_t*)&Bc[(br * 64 + kk * 32 + g * 8) ^ swz(br)];
      }
#pragma unroll
      for (int mi = 0; mi < 4; ++mi)
#pragma unroll
        for (int ni = 0; ni < 4; ++ni)
          acc[mi][ni] = __builtin_amdgcn_mfma_f32_16x16x32_bf16(
              af[mi], bfr[ni], acc[mi][ni], 0, 0, 0);
    }
    BAR2();
    if (t + 2 < NT) stage((t + 2) << 6, cur);
  }

#pragma unroll
  for (int ni = 0; ni < 4; ++ni) {
    int f = n0 + wc * 64 + ni * 16 + l15;
    float bs = bias[f];
#pragma unroll
    for (int mi = 0; mi < 4; ++mi)
#pragma unroll
      for (int i = 0; i < 4; ++i) {
        int m = m0 + wr * 64 + mi * 16 + g * 4 + i;
        oF[(size_t)m * E_ + f] = acc[mi][ni][i] + bs;
      }
  }
}

// ---------------- flash attention -------------------------------------------
// 1 q-tile (64 rows) per block; 4 waves x 16 q-rows; KV tiles of 64.
// Swapped-operand lane-local softmax; lazy max; per-lane partial denom;
// hardware exp2; counted-vmcnt pipeline (T4). LDS 40960 B (4 blocks/CU).
__global__ __launch_bounds__(256) void k_attn(
    const unsigned short* __restrict__ Q,   // [bh][n][64], pre-scaled
    const unsigned short* __restrict__ Kb,  // [bh][n][64]
    const unsigned short* __restrict__ Vt,  // [bh][64][n]
    unsigned short* __restrict__ ctx) {     // [b][n][768]
  __shared__ unsigned short Kl[2][64 * 64];
  __shared__ unsigned short Vl[2][64 * 64];  // [d][k_local]
  __shared__ unsigned short Pl[4][16 * 64];  // per-wave P / O staging [q][*]
  const int bh = blockIdx.x;   // 96
  const int qt = blockIdx.y;   // 16
  const int tid = threadIdx.x;
  const int lane = tid & 63, wv = tid >> 6;
  const int g = lane >> 4, l15 = lane & 15;

  const unsigned short* Qp = Q + ((size_t)bh * N_ + qt * 64 + wv * 16) * HD_;
  bf8_t qf[2];
#pragma unroll
  for (int kk = 0; kk < 2; ++kk)
    qf[kk] = *(const bf8_t*)&Qp[(size_t)l15 * HD_ + kk * 32 + g * 8];

  f4_t o[4] = {};                 // O^T: col q=l15, rows d = di*16 + g*4 + i
  float mrow = -1e30f, lrow = 0.f;  // per-lane running max / PARTIAL denom
  const unsigned short* Kbase = Kb + (size_t)bh * N_ * HD_;
  const unsigned short* Vbase = Vt + (size_t)bh * HD_ * N_;

  auto stage = [&](int t, int buf) {        // 4 loads / thread
#pragma unroll
    for (int i = 0; i < 2; ++i) {
      int e = (i * 256 + tid) * 8;          // 64x64 tile, 16B per lane
      int r = e >> 6;
      int c = (e & 63) ^ swz(r);            // inverse-swizzled source column
      load_lds16(Kbase + (size_t)(t * 64 + r) * HD_ + c, &Kl[buf][e]);
      load_lds16(Vbase + (size_t)r * N_ + (t * 64 + c), &Vl[buf][e]);
    }
  };

  stage(0, 0);
  stage(1, 1);
  unsigned short* Pw = &Pl[wv][0];

  for (int t = 0; t < 16; ++t) {
    const int cur = t & 1;
    if (t + 1 < 16) { WAITV(4); } else { WAITV(0); }
    const unsigned short* Klc = Kl[cur];
    const unsigned short* Vlc = Vl[cur];

    // S^T[kv][q]: s[ni] holds kv = ni*16 + g*4 + i  for q = l15 (exp2 domain)
    f4_t s[4] = {};
    __builtin_amdgcn_s_setprio(1);
#pragma unroll
    for (int ni = 0; ni < 4; ++ni) {
      int krow = ni * 16 + l15;
#pragma unroll
      for (int kk = 0; kk < 2; ++kk) {
        bf8_t kf = *(const bf8_t*)&Klc[(krow * 64 + kk * 32 + g * 8) ^ swz(krow)];
        s[ni] = __builtin_amdgcn_mfma_f32_16x16x32_bf16(kf, qf[kk], s[ni], 0, 0, 0);
      }
    }
    __builtin_amdgcn_s_setprio(0);

    // per-lane max tree (no shuffles in steady state)
    float t0 = F3(s[0][0], s[0][1], s[0][2]);
    float t1 = F3(s[0][3], s[1][0], s[1][1]);
    float t2 = F3(s[1][2], s[1][3], s[2][0]);
    float t3 = F3(s[2][1], s[2][2], s[2][3]);
    float t4 = F3(s[3][0], s[3][1], s[3][2]);
    float mx = fmaxf(F3(F3(t0, t1, t2), t3, t4), s[3][3]);

    // lazy max: reduce + rescale only on breach (P bounded by 2^8)
    if (!__all(mx - mrow <= 8.0f)) {
      float Mx = fmaxf(mx, __shfl_xor(mx, 16, 64));
      Mx = fmaxf(Mx, __shfl_xor(Mx, 32, 64));
      float mnew = fmaxf(mrow, Mx);
      float al = exp2_hw(mrow - mnew);
      lrow *= al;
#pragma unroll
      for (int di = 0; di < 4; ++di)
#pragma unroll
        for (int i = 0; i < 4; ++i) o[di][i] *= al;
      mrow = mnew;
    }

    // exp (hardware, independent ops) + tree-sum (depth 4, reassociated)
    float p0  = exp2_hw(s[0][0] - mrow), p1  = exp2_hw(s[0][1] - mrow);
    float p2  = exp2_hw(s[0][2] - mrow), p3  = exp2_hw(s[0][3] - mrow);
    float p4  = exp2_hw(s[1][0] - mrow), p5  = exp2_hw(s[1][1] - mrow);
    float p6  = exp2_hw(s[1][2] - mrow), p7  = exp2_hw(s[1][3] - mrow);
    float p8  = exp2_hw(s[2][0] - mrow), p9  = exp2_hw(s[2][1] - mrow);
    float p10 = exp2_hw(s[2][2] - mrow), p11 = exp2_hw(s[2][3] - mrow);
    float p12 = exp2_hw(s[3][0] - mrow), p13 = exp2_hw(s[3][1] - mrow);
    float p14 = exp2_hw(s[3][2] - mrow), p15 = exp2_hw(s[3][3] - mrow);
    float a0 = p0 + p1, a1 = p2 + p3, a2 = p4 + p5, a3 = p6 + p7;
    float a4 = p8 + p9, a5 = p10 + p11, a6 = p12 + p13, a7 = p14 + p15;
    float b0 = a0 + a1, b1 = a2 + a3, b2 = a4 + a5, b3 = a6 + a7;
    lrow += (b0 + b1) + (b2 + b3);   // per-lane partial; reduced in epilogue

    // P[q][kv] wave-private, packed b64 writes, row-swizzled
    {
      uint2 pk;
      pk.x = cvt_pk_bf16(p0, p1);   pk.y = cvt_pk_bf16(p2, p3);
      *(uint2*)&Pw[l15 * 64 + ((0 * 16 + g * 4) ^ ((l15 & 7) << 3))] = pk;
      pk.x = cvt_pk_bf16(p4, p5);   pk.y = cvt_pk_bf16(p6, p7);
      *(uint2*)&Pw[l15 * 64 + ((1 * 16 + g * 4) ^ ((l15 & 7) << 3))] = pk;
      pk.x = cvt_pk_bf16(p8, p9);   pk.y = cvt_pk_bf16(p10, p11);
      *(uint2*)&Pw[l15 * 64 + ((2 * 16 + g * 4) ^ ((l15 & 7) << 3))] = pk;
      pk.x = cvt_pk_bf16(p12, p13); pk.y = cvt_pk_bf16(p14, p15);
      *(uint2*)&Pw[l15 * 64 + ((3 * 16 + g * 4) ^ ((l15 & 7) << 3))] = pk;
    }
    asm volatile("s_waitcnt lgkmcnt(0)" ::: "memory");
    __builtin_amdgcn_sched_barrier(0);

    // O^T += mfma(V, P): A = V^T rows (d), B = P rows (q = l15)
    __builtin_amdgcn_s_setprio(1);
#pragma unroll
    for (int kk = 0; kk < 2; ++kk) {
      bf8_t pf = *(const bf8_t*)&Pw[l15 * 64 + ((kk * 32 + g * 8) ^ ((l15 & 7) << 3))];
#pragma unroll
      for (int di = 0; di < 4; ++di) {
        int vrow = di * 16 + l15;
        bf8_t vf = *(const bf8_t*)&Vlc[(vrow * 64 + kk * 32 + g * 8) ^ swz(vrow)];
        o[di] = __builtin_amdgcn_mfma_f32_16x16x32_bf16(vf, pf, o[di], 0, 0, 0);
      }
    }
    __builtin_amdgcn_s_setprio(0);

    // all waves done reading buf[cur]; then refill it for tile t+2
    BAR2();
    if (t + 2 < 16) stage(t + 2, cur);
  }

  // epilogue: reduce per-lane partial denominator once
  lrow += __shfl_xor(lrow, 16, 64);
  lrow += __shfl_xor(lrow, 32, 64);
  float rinv = 1.0f / lrow;
#pragma unroll
  for (int di = 0; di < 4; ++di) {
    uint2 pk;
    pk.x = cvt_pk_bf16(o[di][0] * rinv, o[di][1] * rinv);
    pk.y = cvt_pk_bf16(o[di][2] * rinv, o[di][3] * rinv);
    int oe = l15 * 64 + ((di * 16 + g * 4) ^ ((l15 & 7) << 3));
    *(uint2*)&Pw[oe] = pk;
  }
  asm volatile("s_waitcnt lgkmcnt(0)" ::: "memory");
  __builtin_amdgcn_sched_barrier(0);

  const int bb = bh / H_, h = bh - bb * H_;
  const int rr = lane >> 2, cb = (lane & 3) * 16;
#pragma unroll
  for (int m2 = 0; m2 < 2; ++m2) {
    int e = rr * 64 + ((cb + 8 * m2) ^ ((rr & 7) << 3));
    bf8_t val = *(const bf8_t*)&Pw[e];
    unsigned short* dst =
        ctx + ((size_t)bb * N_ + qt * 64 + wv * 16 + rr) * E_ + h * HD_ + cb + 8 * m2;
    *(bf8_t*)dst = val;
  }
}

// ---------------- launch ----------------
extern "C" void kernel_launch(void* const* d_in, const int* in_sizes, int n_in,
                              void* d_out, int out_size, void* d_ws, size_t ws_size,
                              hipStream_t stream) {
  const float* x     = (const float*)d_in[0];
  const float* ln_g  = (const float*)d_in[1];
  const float* ln_b  = (const float*)d_in[2];
  const float* w_qkv = (const float*)d_in[3];
  const float* b_qkv = (const float*)d_in[4];
  const float* w_out = (const float*)d_in[5];
  const float* b_out = (const float*)d_in[6];
  float* out = (float*)d_out;

  char* ws = (char*)d_ws;
  const size_t SZ = (size_t)M_ * E_ * 2;  // 12.58 MB per bf16 activation
  unsigned short* xn    = (unsigned short*)(ws);
  unsigned short* qb    = (unsigned short*)(ws + SZ);
  unsigned short* kbuf  = (unsigned short*)(ws + 2 * SZ);
  unsigned short* vtb   = (unsigned short*)(ws + 3 * SZ);
  unsigned short* ctx   = (unsigned short*)(ws + 4 * SZ);
  unsigned short* wqkvb = (unsigned short*)(ws + 5 * SZ);
  unsigned short* woutb = (unsigned short*)(ws + 5 * SZ + (size_t)3 * E_ * E_ * 2);

  int n1 = 3 * E_ * E_ / 4;
  k_cast_bf16<<<(n1 + 255) / 256, 256, 0, stream>>>(w_qkv, wqkvb, n1);
  int n2 = E_ * E_ / 4;
  k_cast_bf16<<<(n2 + 255) / 256, 256, 0, stream>>>(w_out, woutb, n2);

  k_ln<<<M_, 192, 0, stream>>>(x, ln_g, ln_b, xn);

  k_gemm_qkv<<<dim3(9, 32), 512, 0, stream>>>(xn, wqkvb, b_qkv, qb, kbuf, vtb);
  k_attn<<<dim3(96, 16), 256, 0, stream>>>(qb, kbuf, vtb, ctx);
  k_gemm_out<<<dim3(6, 64), 256, 0, stream>>>(ctx, woutb, b_out, out);
}

// Round 11
// 159.271 us; speedup vs baseline: 1.1205x; 1.1205x over previous
//
#include <hip/hip_runtime.h>
#include <hip/hip_bf16.h>
#include <stdint.h>

#define B_ 8
#define N_ 1024
#define E_ 768
#define H_ 12
#define HD_ 64
#define M_ (B_ * N_)   // 8192 rows

typedef __attribute__((ext_vector_type(8))) short bf8_t;   // 8 x bf16 (4 VGPR)
typedef __attribute__((ext_vector_type(4))) float f4_t;    // 4 x f32

__device__ __forceinline__ unsigned short f2bf(float f) {
  unsigned u = __builtin_bit_cast(unsigned, f);
  unsigned r = (u + 0x7fffu + ((u >> 16) & 1u)) >> 16;  // RNE
  return (unsigned short)r;
}

__device__ __forceinline__ unsigned cvt_pk_bf16(float lo, float hi) {
  unsigned r;
  asm("v_cvt_pk_bf16_f32 %0, %1, %2" : "=v"(r) : "v"(lo), "v"(hi));
  return r;
}

// single-instruction exp2 (libm exp2f lowers to an __ocml call without
// fast-math; v_exp_f32 is the hardware op, denorm-flush is fine here)
__device__ __forceinline__ float exp2_hw(float x) {
  float r;
  asm("v_exp_f32 %0, %1" : "=v"(r) : "v"(x));
  return r;
}

__device__ __forceinline__ void load_lds16(const void* g, void* l) {
  __builtin_amdgcn_global_load_lds(
      (__attribute__((address_space(1))) void*)(g),
      (__attribute__((address_space(3))) void*)(l), 16, 0, 0);
}

// counted wait (attn only): prefetch stays in flight across the barrier (T4)
#define WAITV(N)                                        \
  asm volatile("s_waitcnt vmcnt(" #N ")" ::: "memory"); \
  __builtin_amdgcn_sched_barrier(0);                    \
  __builtin_amdgcn_s_barrier();                         \
  __builtin_amdgcn_sched_barrier(0);

#define BAR2()                          \
  __builtin_amdgcn_sched_barrier(0);    \
  __builtin_amdgcn_s_barrier();         \
  __builtin_amdgcn_sched_barrier(0);

// XOR swizzle on the 8-elem (16B) chunk within a 64-elem (128B) row (attn).
__device__ __forceinline__ int swz(int row) {
  return ((row ^ (row >> 3)) & 7) << 3;
}
// XOR swizzle on the 8-elem chunk within a 32-elem (64B) row (GEMM BK=32).
// 16-lane groups land 2-way on banks — free (m136).
__device__ __forceinline__ int swz32(int row) {
  return ((row ^ (row >> 2)) & 3) << 3;
}

#define F3(a, b, c) fmaxf(fmaxf((a), (b)), (c))   // fuses to v_max3_f32

// ---------------- weight fp32 -> bf16 cast (vectorized) ----------------
__global__ void k_cast_bf16(const float* __restrict__ in,
                            unsigned short* __restrict__ out, int n4) {
  int i = blockIdx.x * blockDim.x + threadIdx.x;
  if (i < n4) {
    float4 v = ((const float4*)in)[i];
    ushort4 o;
    o.x = f2bf(v.x); o.y = f2bf(v.y); o.z = f2bf(v.z); o.w = f2bf(v.w);
    ((ushort4*)out)[i] = o;
  }
}

// ---------------- LayerNorm -> bf16 (float4 loads, ushort4 stores) ----------
__global__ __launch_bounds__(192) void k_ln(const float* __restrict__ x,
                                            const float* __restrict__ g,
                                            const float* __restrict__ bta,
                                            unsigned short* __restrict__ xn) {
  int row = blockIdx.x;  // 8192
  int t = threadIdx.x;   // 0..191, 192*4 = 768
  float4 v = ((const float4*)(x + (size_t)row * E_))[t];
  float s = v.x + v.y + v.z + v.w;
  float s2 = v.x * v.x + v.y * v.y + v.z * v.z + v.w * v.w;
  for (int off = 32; off; off >>= 1) {
    s += __shfl_xor(s, off, 64);
    s2 += __shfl_xor(s2, off, 64);
  }
  __shared__ float red[6];
  int lane = t & 63, wv = t >> 6;
  if (lane == 0) { red[wv] = s; red[3 + wv] = s2; }
  __syncthreads();
  s = red[0] + red[1] + red[2];
  s2 = red[3] + red[4] + red[5];
  float mu = s * (1.0f / E_);
  float var = s2 * (1.0f / E_) - mu * mu;
  float rstd = rsqrtf(var + 1e-5f);
  float4 gg = ((const float4*)g)[t];
  float4 bb = ((const float4*)bta)[t];
  ushort4 o;
  o.x = f2bf((v.x - mu) * rstd * gg.x + bb.x);
  o.y = f2bf((v.y - mu) * rstd * gg.y + bb.y);
  o.z = f2bf((v.z - mu) * rstd * gg.z + bb.z);
  o.w = f2bf((v.w - mu) * rstd * gg.w + bb.w);
  ((ushort4*)(xn + (size_t)row * E_))[t] = o;
}

// ---------------- GEMM  C = A @ W^T + bias ------------------------------------
// 128x128 tile, BK=32 double-buffer (32 KB LDS -> 4 blocks/CU), round-8
// schedule (stage-ahead + __syncthreads), T1 XCD swizzle, T2 LDS swizzle.
// EPI 0: scatter to Q(*0.125*log2e) [bh][n][d], K [bh][n][d], V^T [bh][d][n]
// EPI 1: dense fp32 [M][E]
template <int EPI>
__global__ __launch_bounds__(256) void k_gemm_bt(
    const unsigned short* __restrict__ A,   // [M][K] bf16
    const unsigned short* __restrict__ W,   // [Nf][K] bf16
    const float* __restrict__ bias,         // [Nf]
    unsigned short* __restrict__ oQ, unsigned short* __restrict__ oK,
    unsigned short* __restrict__ oVt, float* __restrict__ oF,
    int K, int Nf) {
  __shared__ unsigned short Al[2][128 * 32];   // 8 KB each
  __shared__ unsigned short Bl[2][128 * 32];   // total 32 KB
  // bijective XCD-aware block swizzle: contiguous logical tiles per XCD
  const int nbx = Nf >> 7;                  // 18 or 6
  const int nwg = nbx << 6;                 // *64 m-blocks; %8 == 0
  const int orig = blockIdx.y * nbx + blockIdx.x;
  const int id = (orig & 7) * (nwg >> 3) + (orig >> 3);
  const int n0 = (id % nbx) * 128, m0 = (id / nbx) * 128;
  const int tid = threadIdx.x;
  const int lane = tid & 63, wv = tid >> 6;
  const int wr = wv >> 1, wc = wv & 1;      // 2x2 waves of 64x64
  const int g = lane >> 4, l15 = lane & 15;
  f4_t acc[4][4] = {};

  auto stage = [&](int k0, int buf) {       // 4 loads / thread
#pragma unroll
    for (int i = 0; i < 2; ++i) {
      int e = (i * 256 + tid) * 8;          // element idx in 128x32 tile
      int r = e >> 5;
      int c = (e & 31) ^ swz32(r);          // inverse-swizzled source column
      load_lds16(A + (size_t)(m0 + r) * K + (k0 + c), &Al[buf][e]);
      load_lds16(W + (size_t)(n0 + r) * K + (k0 + c), &Bl[buf][e]);
    }
  };

  stage(0, 0);
  __syncthreads();                          // drains vmcnt(0): tile 0 ready
  int cur = 0;

  for (int k0 = 0; k0 < K; k0 += 32) {
    if (k0 + 32 < K) stage(k0 + 32, cur ^ 1);  // prefetch next K-tile; in
                                               // flight across compute
    const unsigned short* Ac = Al[cur];
    const unsigned short* Bc = Bl[cur];
    bf8_t af[4], bfr[4];
#pragma unroll
    for (int mi = 0; mi < 4; ++mi) {
      int ar = wr * 64 + mi * 16 + l15;
      af[mi] = *(const bf8_t*)&Ac[(ar * 32 + g * 8) ^ swz32(ar)];
    }
#pragma unroll
    for (int ni = 0; ni < 4; ++ni) {
      int br = wc * 64 + ni * 16 + l15;
      bfr[ni] = *(const bf8_t*)&Bc[(br * 32 + g * 8) ^ swz32(br)];
    }
#pragma unroll
    for (int mi = 0; mi < 4; ++mi)
#pragma unroll
      for (int ni = 0; ni < 4; ++ni)
        acc[mi][ni] = __builtin_amdgcn_mfma_f32_16x16x32_bf16(
            af[mi], bfr[ni], acc[mi][ni], 0, 0, 0);
    __syncthreads();   // next tile landed; all waves done reading `cur`
    cur ^= 1;
  }

#pragma unroll
  for (int mi = 0; mi < 4; ++mi) {
#pragma unroll
    for (int ni = 0; ni < 4; ++ni) {
      int f = n0 + wc * 64 + ni * 16 + l15;
      float bs = bias[f];
#pragma unroll
      for (int i = 0; i < 4; ++i) {
        int m = m0 + wr * 64 + mi * 16 + g * 4 + i;
        float val = acc[mi][ni][i] + bs;
        if (EPI == 0) {
          int bb = m >> 10, n = m & 1023;
          int which = f / E_;
          int e2 = f - which * E_;
          int h = e2 >> 6, d = e2 & 63;
          size_t qk = (((size_t)bb * H_ + h) * N_ + n) * HD_ + d;
          if (which == 0) oQ[qk] = f2bf(val * 0.1803368801f);  // 0.125*log2(e)
          else if (which == 1) oK[qk] = f2bf(val);
          else oVt[(((size_t)bb * H_ + h) * HD_ + d) * N_ + n] = f2bf(val);
        } else {
          oF[(size_t)m * E_ + f] = val;
        }
      }
    }
  }
}

// ---------------- flash attention -------------------------------------------
// 1 q-tile (64 rows) per block; 4 waves x 16 q-rows; KV tiles of 64.
// Swapped-operand lane-local softmax; lazy max; per-lane partial denom;
// hardware exp2; counted-vmcnt pipeline (T4). LDS 40960 B (4 blocks/CU).
__global__ __launch_bounds__(256) void k_attn(
    const unsigned short* __restrict__ Q,   // [bh][n][64], pre-scaled
    const unsigned short* __restrict__ Kb,  // [bh][n][64]
    const unsigned short* __restrict__ Vt,  // [bh][64][n]
    unsigned short* __restrict__ ctx) {     // [b][n][768]
  __shared__ unsigned short Kl[2][64 * 64];
  __shared__ unsigned short Vl[2][64 * 64];  // [d][k_local]
  __shared__ unsigned short Pl[4][16 * 64];  // per-wave P / O staging [q][*]
  const int bh = blockIdx.x;   // 96
  const int qt = blockIdx.y;   // 16
  const int tid = threadIdx.x;
  const int lane = tid & 63, wv = tid >> 6;
  const int g = lane >> 4, l15 = lane & 15;

  const unsigned short* Qp = Q + ((size_t)bh * N_ + qt * 64 + wv * 16) * HD_;
  bf8_t qf[2];
#pragma unroll
  for (int kk = 0; kk < 2; ++kk)
    qf[kk] = *(const bf8_t*)&Qp[(size_t)l15 * HD_ + kk * 32 + g * 8];

  f4_t o[4] = {};                 // O^T: col q=l15, rows d = di*16 + g*4 + i
  float mrow = -1e30f, lrow = 0.f;  // per-lane running max / PARTIAL denom
  const unsigned short* Kbase = Kb + (size_t)bh * N_ * HD_;
  const unsigned short* Vbase = Vt + (size_t)bh * HD_ * N_;

  auto stage = [&](int t, int buf) {        // 4 loads / thread
#pragma unroll
    for (int i = 0; i < 2; ++i) {
      int e = (i * 256 + tid) * 8;          // 64x64 tile, 16B per lane
      int r = e >> 6;
      int c = (e & 63) ^ swz(r);            // inverse-swizzled source column
      load_lds16(Kbase + (size_t)(t * 64 + r) * HD_ + c, &Kl[buf][e]);
      load_lds16(Vbase + (size_t)r * N_ + (t * 64 + c), &Vl[buf][e]);
    }
  };

  stage(0, 0);
  stage(1, 1);
  unsigned short* Pw = &Pl[wv][0];

  for (int t = 0; t < 16; ++t) {
    const int cur = t & 1;
    if (t + 1 < 16) { WAITV(4); } else { WAITV(0); }
    const unsigned short* Klc = Kl[cur];
    const unsigned short* Vlc = Vl[cur];

    // S^T[kv][q]: s[ni] holds kv = ni*16 + g*4 + i  for q = l15 (exp2 domain)
    f4_t s[4] = {};
    __builtin_amdgcn_s_setprio(1);
#pragma unroll
    for (int ni = 0; ni < 4; ++ni) {
      int krow = ni * 16 + l15;
#pragma unroll
      for (int kk = 0; kk < 2; ++kk) {
        bf8_t kf = *(const bf8_t*)&Klc[(krow * 64 + kk * 32 + g * 8) ^ swz(krow)];
        s[ni] = __builtin_amdgcn_mfma_f32_16x16x32_bf16(kf, qf[kk], s[ni], 0, 0, 0);
      }
    }
    __builtin_amdgcn_s_setprio(0);

    // per-lane max tree (no shuffles in steady state)
    float t0 = F3(s[0][0], s[0][1], s[0][2]);
    float t1 = F3(s[0][3], s[1][0], s[1][1]);
    float t2 = F3(s[1][2], s[1][3], s[2][0]);
    float t3 = F3(s[2][1], s[2][2], s[2][3]);
    float t4 = F3(s[3][0], s[3][1], s[3][2]);
    float mx = fmaxf(F3(F3(t0, t1, t2), t3, t4), s[3][3]);

    // lazy max: reduce + rescale only on breach (P bounded by 2^8)
    if (!__all(mx - mrow <= 8.0f)) {
      float Mx = fmaxf(mx, __shfl_xor(mx, 16, 64));
      Mx = fmaxf(Mx, __shfl_xor(Mx, 32, 64));
      float mnew = fmaxf(mrow, Mx);
      float al = exp2_hw(mrow - mnew);
      lrow *= al;
#pragma unroll
      for (int di = 0; di < 4; ++di)
#pragma unroll
        for (int i = 0; i < 4; ++i) o[di][i] *= al;
      mrow = mnew;
    }

    // exp (hardware, independent ops) + tree-sum (depth 4, reassociated)
    float p0  = exp2_hw(s[0][0] - mrow), p1  = exp2_hw(s[0][1] - mrow);
    float p2  = exp2_hw(s[0][2] - mrow), p3  = exp2_hw(s[0][3] - mrow);
    float p4  = exp2_hw(s[1][0] - mrow), p5  = exp2_hw(s[1][1] - mrow);
    float p6  = exp2_hw(s[1][2] - mrow), p7  = exp2_hw(s[1][3] - mrow);
    float p8  = exp2_hw(s[2][0] - mrow), p9  = exp2_hw(s[2][1] - mrow);
    float p10 = exp2_hw(s[2][2] - mrow), p11 = exp2_hw(s[2][3] - mrow);
    float p12 = exp2_hw(s[3][0] - mrow), p13 = exp2_hw(s[3][1] - mrow);
    float p14 = exp2_hw(s[3][2] - mrow), p15 = exp2_hw(s[3][3] - mrow);
    float a0 = p0 + p1, a1 = p2 + p3, a2 = p4 + p5, a3 = p6 + p7;
    float a4 = p8 + p9, a5 = p10 + p11, a6 = p12 + p13, a7 = p14 + p15;
    float b0 = a0 + a1, b1 = a2 + a3, b2 = a4 + a5, b3 = a6 + a7;
    lrow += (b0 + b1) + (b2 + b3);   // per-lane partial; reduced in epilogue

    // P[q][kv] wave-private, packed b64 writes, row-swizzled
    {
      uint2 pk;
      pk.x = cvt_pk_bf16(p0, p1);   pk.y = cvt_pk_bf16(p2, p3);
      *(uint2*)&Pw[l15 * 64 + ((0 * 16 + g * 4) ^ ((l15 & 7) << 3))] = pk;
      pk.x = cvt_pk_bf16(p4, p5);   pk.y = cvt_pk_bf16(p6, p7);
      *(uint2*)&Pw[l15 * 64 + ((1 * 16 + g * 4) ^ ((l15 & 7) << 3))] = pk;
      pk.x = cvt_pk_bf16(p8, p9);   pk.y = cvt_pk_bf16(p10, p11);
      *(uint2*)&Pw[l15 * 64 + ((2 * 16 + g * 4) ^ ((l15 & 7) << 3))] = pk;
      pk.x = cvt_pk_bf16(p12, p13); pk.y = cvt_pk_bf16(p14, p15);
      *(uint2*)&Pw[l15 * 64 + ((3 * 16 + g * 4) ^ ((l15 & 7) << 3))] = pk;
    }
    asm volatile("s_waitcnt lgkmcnt(0)" ::: "memory");
    __builtin_amdgcn_sched_barrier(0);

    // O^T += mfma(V, P): A = V^T rows (d), B = P rows (q = l15)
    __builtin_amdgcn_s_setprio(1);
#pragma unroll
    for (int kk = 0; kk < 2; ++kk) {
      bf8_t pf = *(const bf8_t*)&Pw[l15 * 64 + ((kk * 32 + g * 8) ^ ((l15 & 7) << 3))];
#pragma unroll
      for (int di = 0; di < 4; ++di) {
        int vrow = di * 16 + l15;
        bf8_t vf = *(const bf8_t*)&Vlc[(vrow * 64 + kk * 32 + g * 8) ^ swz(vrow)];
        o[di] = __builtin_amdgcn_mfma_f32_16x16x32_bf16(vf, pf, o[di], 0, 0, 0);
      }
    }
    __builtin_amdgcn_s_setprio(0);

    // all waves done reading buf[cur]; then refill it for tile t+2
    BAR2();
    if (t + 2 < 16) stage(t + 2, cur);
  }

  // epilogue: reduce per-lane partial denominator once
  lrow += __shfl_xor(lrow, 16, 64);
  lrow += __shfl_xor(lrow, 32, 64);
  float rinv = 1.0f / lrow;
#pragma unroll
  for (int di = 0; di < 4; ++di) {
    uint2 pk;
    pk.x = cvt_pk_bf16(o[di][0] * rinv, o[di][1] * rinv);
    pk.y = cvt_pk_bf16(o[di][2] * rinv, o[di][3] * rinv);
    int oe = l15 * 64 + ((di * 16 + g * 4) ^ ((l15 & 7) << 3));
    *(uint2*)&Pw[oe] = pk;
  }
  asm volatile("s_waitcnt lgkmcnt(0)" ::: "memory");
  __builtin_amdgcn_sched_barrier(0);

  const int bb = bh / H_, h = bh - bb * H_;
  const int rr = lane >> 2, cb = (lane & 3) * 16;
#pragma unroll
  for (int m2 = 0; m2 < 2; ++m2) {
    int e = rr * 64 + ((cb + 8 * m2) ^ ((rr & 7) << 3));
    bf8_t val = *(const bf8_t*)&Pw[e];
    unsigned short* dst =
        ctx + ((size_t)bb * N_ + qt * 64 + wv * 16 + rr) * E_ + h * HD_ + cb + 8 * m2;
    *(bf8_t*)dst = val;
  }
}

// ---------------- launch ----------------
extern "C" void kernel_launch(void* const* d_in, const int* in_sizes, int n_in,
                              void* d_out, int out_size, void* d_ws, size_t ws_size,
                              hipStream_t stream) {
  const float* x     = (const float*)d_in[0];
  const float* ln_g  = (const float*)d_in[1];
  const float* ln_b  = (const float*)d_in[2];
  const float* w_qkv = (const float*)d_in[3];
  const float* b_qkv = (const float*)d_in[4];
  const float* w_out = (const float*)d_in[5];
  const float* b_out = (const float*)d_in[6];
  float* out = (float*)d_out;

  char* ws = (char*)d_ws;
  const size_t SZ = (size_t)M_ * E_ * 2;  // 12.58 MB per bf16 activation
  unsigned short* xn    = (unsigned short*)(ws);
  unsigned short* qb    = (unsigned short*)(ws + SZ);
  unsigned short* kbuf  = (unsigned short*)(ws + 2 * SZ);
  unsigned short* vtb   = (unsigned short*)(ws + 3 * SZ);
  unsigned short* ctx   = (unsigned short*)(ws + 4 * SZ);
  unsigned short* wqkvb = (unsigned short*)(ws + 5 * SZ);
  unsigned short* woutb = (unsigned short*)(ws + 5 * SZ + (size_t)3 * E_ * E_ * 2);

  int n1 = 3 * E_ * E_ / 4;
  k_cast_bf16<<<(n1 + 255) / 256, 256, 0, stream>>>(w_qkv, wqkvb, n1);
  int n2 = E_ * E_ / 4;
  k_cast_bf16<<<(n2 + 255) / 256, 256, 0, stream>>>(w_out, woutb, n2);

  k_ln<<<M_, 192, 0, stream>>>(x, ln_g, ln_b, xn);

  k_gemm_bt<0><<<dim3(18, 64), 256, 0, stream>>>(xn, wqkvb, b_qkv, qb, kbuf, vtb,
                                                 nullptr, E_, 3 * E_);
  k_attn<<<dim3(96, 16), 256, 0, stream>>>(qb, kbuf, vtb, ctx);
  k_gemm_bt<1><<<dim3(6, 64), 256, 0, stream>>>(ctx, woutb, b_out, nullptr, nullptr,
                                                nullptr, out, E_, E_);
}

// Round 12
// 137.624 us; speedup vs baseline: 1.2968x; 1.1573x over previous
//
#include <hip/hip_runtime.h>
#include <hip/hip_bf16.h>
#include <stdint.h>

#define B_ 8
#define N_ 1024
#define E_ 768
#define H_ 12
#define HD_ 64
#define M_ (B_ * N_)   // 8192 rows

typedef __attribute__((ext_vector_type(8))) short bf8_t;    // 8 x bf16
typedef __attribute__((ext_vector_type(4))) float f4_t;     // 4 x f32
typedef __attribute__((ext_vector_type(16))) float f16_t;   // 16 x f32 (32x32 acc)

__device__ __forceinline__ unsigned short f2bf(float f) {
  unsigned u = __builtin_bit_cast(unsigned, f);
  unsigned r = (u + 0x7fffu + ((u >> 16) & 1u)) >> 16;  // RNE
  return (unsigned short)r;
}

__device__ __forceinline__ unsigned cvt_pk_bf16(float lo, float hi) {
  unsigned r;
  asm("v_cvt_pk_bf16_f32 %0, %1, %2" : "=v"(r) : "v"(lo), "v"(hi));
  return r;
}

__device__ __forceinline__ float exp2_hw(float x) {
  float r;
  asm("v_exp_f32 %0, %1" : "=v"(r) : "v"(x));
  return r;
}

__device__ __forceinline__ void load_lds16(const void* g, void* l) {
  __builtin_amdgcn_global_load_lds(
      (__attribute__((address_space(1))) void*)(g),
      (__attribute__((address_space(3))) void*)(l), 16, 0, 0);
}

#define WAITV(N)                                        \
  asm volatile("s_waitcnt vmcnt(" #N ")" ::: "memory"); \
  __builtin_amdgcn_sched_barrier(0);                    \
  __builtin_amdgcn_s_barrier();                         \
  __builtin_amdgcn_sched_barrier(0);

#define BAR2()                          \
  __builtin_amdgcn_sched_barrier(0);    \
  __builtin_amdgcn_s_barrier();         \
  __builtin_amdgcn_sched_barrier(0);

// XOR swizzle on the 8-elem (16B) chunk within a 64-elem (128B) row.
__device__ __forceinline__ int swz(int row) {
  return ((row ^ (row >> 3)) & 7) << 3;
}

#define F3(a, b, c) fmaxf(fmaxf((a), (b)), (c))   // fuses to v_max3_f32

// ---------------- weight fp32 -> bf16 cast (vectorized) ----------------
__global__ void k_cast_bf16(const float* __restrict__ in,
                            unsigned short* __restrict__ out, int n4) {
  int i = blockIdx.x * blockDim.x + threadIdx.x;
  if (i < n4) {
    float4 v = ((const float4*)in)[i];
    ushort4 o;
    o.x = f2bf(v.x); o.y = f2bf(v.y); o.z = f2bf(v.z); o.w = f2bf(v.w);
    ((ushort4*)out)[i] = o;
  }
}

// ---------------- LayerNorm -> bf16 ----------------
__global__ __launch_bounds__(192) void k_ln(const float* __restrict__ x,
                                            const float* __restrict__ g,
                                            const float* __restrict__ bta,
                                            unsigned short* __restrict__ xn) {
  int row = blockIdx.x;  // 8192
  int t = threadIdx.x;   // 0..191
  float4 v = ((const float4*)(x + (size_t)row * E_))[t];
  float s = v.x + v.y + v.z + v.w;
  float s2 = v.x * v.x + v.y * v.y + v.z * v.z + v.w * v.w;
  for (int off = 32; off; off >>= 1) {
    s += __shfl_xor(s, off, 64);
    s2 += __shfl_xor(s2, off, 64);
  }
  __shared__ float red[6];
  int lane = t & 63, wv = t >> 6;
  if (lane == 0) { red[wv] = s; red[3 + wv] = s2; }
  __syncthreads();
  s = red[0] + red[1] + red[2];
  s2 = red[3] + red[4] + red[5];
  float mu = s * (1.0f / E_);
  float var = s2 * (1.0f / E_) - mu * mu;
  float rstd = rsqrtf(var + 1e-5f);
  float4 gg = ((const float4*)g)[t];
  float4 bb = ((const float4*)bta)[t];
  ushort4 o;
  o.x = f2bf((v.x - mu) * rstd * gg.x + bb.x);
  o.y = f2bf((v.y - mu) * rstd * gg.y + bb.y);
  o.z = f2bf((v.z - mu) * rstd * gg.z + bb.z);
  o.w = f2bf((v.w - mu) * rstd * gg.w + bb.w);
  ((ushort4*)(xn + (size_t)row * E_))[t] = o;
}

// ---------------- GEMM  C = A @ W^T + bias  (round-8 config) -----------------
// BK=64 double-buffer, stage-ahead + __syncthreads, T1 XCD swizzle, T2 swizzle.
template <int EPI>
__global__ __launch_bounds__(256) void k_gemm_bt(
    const unsigned short* __restrict__ A,   // [M][K] bf16
    const unsigned short* __restrict__ W,   // [Nf][K] bf16
    const float* __restrict__ bias,         // [Nf]
    unsigned short* __restrict__ oQ, unsigned short* __restrict__ oK,
    unsigned short* __restrict__ oVt, float* __restrict__ oF,
    int K, int Nf) {
  __shared__ unsigned short Al[2][128 * 64];
  __shared__ unsigned short Bl[2][128 * 64];
  const int nbx = Nf >> 7;                  // 18 or 6
  const int nwg = nbx << 6;
  const int orig = blockIdx.y * nbx + blockIdx.x;
  const int id = (orig & 7) * (nwg >> 3) + (orig >> 3);
  const int n0 = (id % nbx) * 128, m0 = (id / nbx) * 128;
  const int tid = threadIdx.x;
  const int lane = tid & 63, wv = tid >> 6;
  const int wr = wv >> 1, wc = wv & 1;
  const int g = lane >> 4, l15 = lane & 15;
  f4_t acc[4][4] = {};

  auto stage = [&](int k0, int buf) {
#pragma unroll
    for (int i = 0; i < 4; ++i) {
      int e = (i * 256 + tid) * 8;
      int r = e >> 6;
      int c = (e & 63) ^ swz(r);
      load_lds16(A + (size_t)(m0 + r) * K + (k0 + c), &Al[buf][e]);
      load_lds16(W + (size_t)(n0 + r) * K + (k0 + c), &Bl[buf][e]);
    }
  };

  stage(0, 0);
  __syncthreads();
  int cur = 0;

  for (int k0 = 0; k0 < K; k0 += 64) {
    if (k0 + 64 < K) stage(k0 + 64, cur ^ 1);
    const unsigned short* Ac = Al[cur];
    const unsigned short* Bc = Bl[cur];
#pragma unroll
    for (int kk = 0; kk < 2; ++kk) {
      bf8_t af[4], bfr[4];
#pragma unroll
      for (int mi = 0; mi < 4; ++mi) {
        int ar = wr * 64 + mi * 16 + l15;
        af[mi] = *(const bf8_t*)&Ac[(ar * 64 + kk * 32 + g * 8) ^ swz(ar)];
      }
#pragma unroll
      for (int ni = 0; ni < 4; ++ni) {
        int br = wc * 64 + ni * 16 + l15;
        bfr[ni] = *(const bf8_t*)&Bc[(br * 64 + kk * 32 + g * 8) ^ swz(br)];
      }
#pragma unroll
      for (int mi = 0; mi < 4; ++mi)
#pragma unroll
        for (int ni = 0; ni < 4; ++ni)
          acc[mi][ni] = __builtin_amdgcn_mfma_f32_16x16x32_bf16(
              af[mi], bfr[ni], acc[mi][ni], 0, 0, 0);
    }
    __syncthreads();
    cur ^= 1;
  }

#pragma unroll
  for (int mi = 0; mi < 4; ++mi) {
#pragma unroll
    for (int ni = 0; ni < 4; ++ni) {
      int f = n0 + wc * 64 + ni * 16 + l15;
      float bs = bias[f];
#pragma unroll
      for (int i = 0; i < 4; ++i) {
        int m = m0 + wr * 64 + mi * 16 + g * 4 + i;
        float val = acc[mi][ni][i] + bs;
        if (EPI == 0) {
          int bb = m >> 10, n = m & 1023;
          int which = f / E_;
          int e2 = f - which * E_;
          int h = e2 >> 6, d = e2 & 63;
          size_t qk = (((size_t)bb * H_ + h) * N_ + n) * HD_ + d;
          if (which == 0) oQ[qk] = f2bf(val * 0.1803368801f);  // 0.125*log2(e)
          else if (which == 1) oK[qk] = f2bf(val);
          else oVt[(((size_t)bb * H_ + h) * HD_ + d) * N_ + n] = f2bf(val);
        } else {
          oF[(size_t)m * E_ + f] = val;
        }
      }
    }
  }
}

// ---------------- flash attention: 32x32 MFMA, in-register P ------------------
// 4 waves x 32 q-rows (128 q/block, grid 768 = 3 blocks/CU, full residency).
// S^T = mfma32(K,Q): lane owns q = lane&31, 32 kv values (2 frags x 16 regs,
// kv = 32f + (r&3) + 8(r>>2) + 4hi). P -> PV B-operand fully in-register via
// cvt_pk + v_permlane32_swap (T12). O^T = mfma32(V^T, P). No P LDS.
__global__ __launch_bounds__(256, 3) void k_attn(
    const unsigned short* __restrict__ Q,   // [bh][n][64], pre-scaled
    const unsigned short* __restrict__ Kb,  // [bh][n][64]
    const unsigned short* __restrict__ Vt,  // [bh][64][n]
    unsigned short* __restrict__ ctx) {     // [b][n][768]
  __shared__ unsigned short Kl[2][64 * 64];  // [kv][d], swizzled
  __shared__ unsigned short Vl[2][64 * 64];  // [d][kv], swizzled
  const int bh = blockIdx.x;   // 96
  const int qt = blockIdx.y;   // 8  (128 q-rows per block)
  const int tid = threadIdx.x;
  const int lane = tid & 63, wv = tid >> 6;
  const int q5 = lane & 31, hi = lane >> 5;

  // Q B-operand fragments: slice s needs Q[q][d = 16s + 8hi + 0..7]
  const unsigned short* Qp =
      Q + ((size_t)bh * N_ + qt * 128 + wv * 32 + q5) * HD_;
  bf8_t qf[4];
#pragma unroll
  for (int s = 0; s < 4; ++s)
    qf[s] = *(const bf8_t*)&Qp[s * 16 + hi * 8];

  f16_t o0 = {}, o1 = {};        // O^T frags: col q=q5, rows d = frag*32 + cr(r,hi)
  float mrow = -1e30f, lrow = 0.f;
  const unsigned short* Kbase = Kb + (size_t)bh * N_ * HD_;
  const unsigned short* Vbase = Vt + (size_t)bh * HD_ * N_;

  auto stage = [&](int t, int buf) {        // 4 loads / thread
#pragma unroll
    for (int i = 0; i < 2; ++i) {
      int e = (i * 256 + tid) * 8;
      int r = e >> 6;
      int c = (e & 63) ^ swz(r);
      load_lds16(Kbase + (size_t)(t * 64 + r) * HD_ + c, &Kl[buf][e]);
      load_lds16(Vbase + (size_t)r * N_ + (t * 64 + c), &Vl[buf][e]);
    }
  };

  stage(0, 0);
  stage(1, 1);

  for (int t = 0; t < 16; ++t) {
    const int cur = t & 1;
    if (t + 1 < 16) { WAITV(4); } else { WAITV(0); }
    const unsigned short* Klc = Kl[cur];
    const unsigned short* Vlc = Vl[cur];

    // QK^T: S^T[kv][q], 2 kv-frags x 4 d-slices
    f16_t s0 = {}, s1 = {};
    __builtin_amdgcn_s_setprio(1);
#pragma unroll
    for (int s = 0; s < 4; ++s) {
      int doff = s * 16 + hi * 8;
      bf8_t k0 = *(const bf8_t*)&Klc[(q5 * 64 + doff) ^ swz(q5)];
      bf8_t k1 = *(const bf8_t*)&Klc[((32 + q5) * 64 + doff) ^ swz(32 + q5)];
      s0 = __builtin_amdgcn_mfma_f32_32x32x16_bf16(k0, qf[s], s0, 0, 0, 0);
      s1 = __builtin_amdgcn_mfma_f32_32x32x16_bf16(k1, qf[s], s1, 0, 0, 0);
    }
    __builtin_amdgcn_s_setprio(0);

    // per-lane max over 32 values (max3 tree, no shuffles in steady state)
    float v0 = F3(s0[0], s0[1], s0[2]),   v1 = F3(s0[3], s0[4], s0[5]);
    float v2 = F3(s0[6], s0[7], s0[8]),   v3 = F3(s0[9], s0[10], s0[11]);
    float v4 = F3(s0[12], s0[13], s0[14]), v5 = F3(s0[15], s1[0], s1[1]);
    float v6 = F3(s1[2], s1[3], s1[4]),   v7 = F3(s1[5], s1[6], s1[7]);
    float v8 = F3(s1[8], s1[9], s1[10]),  v9 = F3(s1[11], s1[12], s1[13]);
    float w0 = F3(v0, v1, v2), w1 = F3(v3, v4, v5);
    float w2 = F3(v6, v7, v8), w3 = F3(v9, s1[14], s1[15]);
    float mx = fmaxf(F3(w0, w1, w2), w3);

    // lazy max: row is split across lane and lane^32 only
    if (!__all(mx - mrow <= 8.0f)) {
      float Mx = fmaxf(mx, __shfl_xor(mx, 32, 64));
      float mnew = fmaxf(mrow, Mx);
      float al = exp2_hw(mrow - mnew);
      lrow *= al;
#pragma unroll
      for (int r = 0; r < 16; ++r) { o0[r] *= al; o1[r] *= al; }
      mrow = mnew;
    }

    // exp + per-lane partial sum
    float p[32];
#pragma unroll
    for (int r = 0; r < 16; ++r) p[r] = exp2_hw(s0[r] - mrow);
#pragma unroll
    for (int r = 0; r < 16; ++r) p[16 + r] = exp2_hw(s1[r] - mrow);
    float acc0 = 0.f, acc1 = 0.f, acc2 = 0.f, acc3 = 0.f;
#pragma unroll
    for (int r = 0; r < 8; ++r) {
      acc0 += p[r]; acc1 += p[8 + r]; acc2 += p[16 + r]; acc3 += p[24 + r];
    }
    lrow += (acc0 + acc1) + (acc2 + acc3);

    // P -> PV B-operand in-register: per slice 4 cvt_pk + 2 permlane32_swap.
    // slice s uses p[8s..8s+7]; swap exchanges A.hi <-> B.lo:
    //   A' = {A.lo, B.lo} (words j0), B' = {A.hi, B.hi} (words j2)
    unsigned pj[4][4];
#pragma unroll
    for (int s = 0; s < 4; ++s) {
      unsigned Ax = cvt_pk_bf16(p[8 * s + 0], p[8 * s + 1]);
      unsigned Cx = cvt_pk_bf16(p[8 * s + 2], p[8 * s + 3]);
      unsigned Ex = cvt_pk_bf16(p[8 * s + 4], p[8 * s + 5]);
      unsigned Fx = cvt_pk_bf16(p[8 * s + 6], p[8 * s + 7]);
      asm volatile("v_permlane32_swap_b32 %0, %1" : "+v"(Ax), "+v"(Ex));
      asm volatile("v_permlane32_swap_b32 %0, %1" : "+v"(Cx), "+v"(Fx));
      pj[s][0] = Ax; pj[s][1] = Cx; pj[s][2] = Ex; pj[s][3] = Fx;
    }

    // PV: O^T += mfma32(V^T, P), 2 d-frags x 4 kv-slices
    __builtin_amdgcn_s_setprio(1);
#pragma unroll
    for (int s = 0; s < 4; ++s) {
      int koff = s * 16 + hi * 8;
      bf8_t pb;
      *(uint4*)&pb = *(uint4*)&pj[s][0];
      bf8_t vv0 = *(const bf8_t*)&Vlc[(q5 * 64 + koff) ^ swz(q5)];
      bf8_t vv1 = *(const bf8_t*)&Vlc[((32 + q5) * 64 + koff) ^ swz(32 + q5)];
      o0 = __builtin_amdgcn_mfma_f32_32x32x16_bf16(vv0, pb, o0, 0, 0, 0);
      o1 = __builtin_amdgcn_mfma_f32_32x32x16_bf16(vv1, pb, o1, 0, 0, 0);
    }
    __builtin_amdgcn_s_setprio(0);

    BAR2();
    if (t + 2 < 16) stage(t + 2, cur);
  }

  // epilogue: denominator (row split over lane^32), normalize, transpose via LDS
  lrow += __shfl_xor(lrow, 32, 64);
  float rinv = 1.0f / lrow;

  unsigned short* Ol = &Kl[0][0] + wv * 2048;   // per-wave 32q x 64d region
#pragma unroll
  for (int f = 0; f < 2; ++f) {
#pragma unroll
    for (int r = 0; r < 16; r += 2) {
      int d = (r & 3) + 8 * (r >> 2) + 4 * hi + 32 * f;
      float lo = (f ? o1[r] : o0[r]) * rinv;
      float hi2 = (f ? o1[r + 1] : o0[r + 1]) * rinv;
      unsigned pk = cvt_pk_bf16(lo, hi2);
      *(unsigned*)&Ol[q5 * 64 + (d ^ ((q5 & 7) << 3))] = pk;
    }
  }
  asm volatile("s_waitcnt lgkmcnt(0)" ::: "memory");
  __builtin_amdgcn_sched_barrier(0);

  const int bb = bh / H_, h = bh - bb * H_;
  const int qq = lane >> 1;
#pragma unroll
  for (int k = 0; k < 4; ++k) {
    int c = (lane & 1) * 4 + k;                 // 16B chunk (8 d-elems)
    bf8_t val = *(const bf8_t*)&Ol[qq * 64 + ((c * 8) ^ ((qq & 7) << 3))];
    unsigned short* dst = ctx +
        ((size_t)bb * N_ + qt * 128 + wv * 32 + qq) * E_ + h * HD_ + c * 8;
    *(bf8_t*)dst = val;
  }
}

// ---------------- launch ----------------
extern "C" void kernel_launch(void* const* d_in, const int* in_sizes, int n_in,
                              void* d_out, int out_size, void* d_ws, size_t ws_size,
                              hipStream_t stream) {
  const float* x     = (const float*)d_in[0];
  const float* ln_g  = (const float*)d_in[1];
  const float* ln_b  = (const float*)d_in[2];
  const float* w_qkv = (const float*)d_in[3];
  const float* b_qkv = (const float*)d_in[4];
  const float* w_out = (const float*)d_in[5];
  const float* b_out = (const float*)d_in[6];
  float* out = (float*)d_out;

  char* ws = (char*)d_ws;
  const size_t SZ = (size_t)M_ * E_ * 2;
  unsigned short* xn    = (unsigned short*)(ws);
  unsigned short* qb    = (unsigned short*)(ws + SZ);
  unsigned short* kbuf  = (unsigned short*)(ws + 2 * SZ);
  unsigned short* vtb   = (unsigned short*)(ws + 3 * SZ);
  unsigned short* ctx   = (unsigned short*)(ws + 4 * SZ);
  unsigned short* wqkvb = (unsigned short*)(ws + 5 * SZ);
  unsigned short* woutb = (unsigned short*)(ws + 5 * SZ + (size_t)3 * E_ * E_ * 2);

  int n1 = 3 * E_ * E_ / 4;
  k_cast_bf16<<<(n1 + 255) / 256, 256, 0, stream>>>(w_qkv, wqkvb, n1);
  int n2 = E_ * E_ / 4;
  k_cast_bf16<<<(n2 + 255) / 256, 256, 0, stream>>>(w_out, woutb, n2);

  k_ln<<<M_, 192, 0, stream>>>(x, ln_g, ln_b, xn);

  k_gemm_bt<0><<<dim3(18, 64), 256, 0, stream>>>(xn, wqkvb, b_qkv, qb, kbuf, vtb,
                                                 nullptr, E_, 3 * E_);
  k_attn<<<dim3(96, 8), 256, 0, stream>>>(qb, kbuf, vtb, ctx);
  k_gemm_bt<1><<<dim3(6, 64), 256, 0, stream>>>(ctx, woutb, b_out, nullptr, nullptr,
                                                nullptr, out, E_, E_);
}